// Round 1
// 630.759 us; speedup vs baseline: 1.0073x; 1.0073x over previous
//
#include <hip/hip_runtime.h>
#include <hip/hip_bf16.h>

typedef float f32x4 __attribute__((ext_vector_type(4)));
typedef int   i32x4 __attribute__((ext_vector_type(4)));

#define DELTA 5e-5f
#define LIST_CAP 4194304

// ---------------- weight prep: fold BN, per-cout i8 digit decomposition -------
// S = max_k |w*inv| / 127 (rounded to f32, used exactly on both sides).
// d0 = rint(w/S); r -= d0*S; d1 = rint(254 r/S); r -= d1*S/254;
// d2 = rint(64516 r/S)  (conv1 only; 64516 = 254*254 = 508*127, so |d2|<=127)
// layout per conv per split: wp[kc][cout][kk] bytes, k=r*128+cin, kc=k>>6, kk=k&63
// split stride 147456 B; conv2 region starts at 442368.
__global__ void prep_kernel(const float* __restrict__ w1, const float* __restrict__ g1,
                            const float* __restrict__ b1, const float* __restrict__ m1,
                            const float* __restrict__ v1,
                            const float* __restrict__ w2, const float* __restrict__ g2,
                            const float* __restrict__ b2, const float* __restrict__ m2,
                            const float* __restrict__ v2,
                            signed char* __restrict__ wp, float* __restrict__ off,
                            float* __restrict__ scl, int* __restrict__ cnt)
{
    __shared__ double red[128];
    const int blk  = blockIdx.x;       // 256 blocks = conv*128 + cout
    const int conv = blk >> 7;
    const int cout = blk & 127;
    const int cin  = threadIdx.x;      // 128 threads
    const float* w  = conv ? w2 : w1;
    const float* g  = conv ? g2 : g1;
    const float* bb = conv ? b2 : b1;
    const float* mm = conv ? m2 : m1;
    const float* vr = conv ? v2 : v1;
    const float invf = g[cout] / sqrtf(vr[cout] + 1e-5f);
    double wv[9];
    double mx = 0.0;
#pragma unroll
    for (int r = 0; r < 9; ++r) {
        wv[r] = (double)w[(size_t)(cout * 128 + cin) * 9 + r] * (double)invf;
        mx = fmax(mx, fabs(wv[r]));
    }
    red[cin] = mx;
    __syncthreads();
    for (int s = 64; s > 0; s >>= 1) {
        if (cin < s) red[cin] = fmax(red[cin], red[cin + s]);
        __syncthreads();
    }
    double S = red[0];
    S = (S > 0.0) ? (double)(float)(S / 127.0) : 1.0;
    const size_t base = conv ? (size_t)442368 : (size_t)0;
#pragma unroll
    for (int r = 0; r < 9; ++r) {
        double x = wv[r];
        const int k = r * 128 + cin;
        const size_t pos = ((size_t)(k >> 6) * 128 + cout) * 64 + (k & 63);
        int d0 = (int)rint(x / S);          x -= (double)d0 * S;
        int d1 = (int)rint(x * 254.0 / S);  x -= (double)d1 * S / 254.0;
        wp[base + pos]          = (signed char)d0;
        wp[base + 147456 + pos] = (signed char)d1;
        if (conv == 0) {
            int d2 = (int)rint(x * 64516.0 / S);
            wp[base + 294912 + pos] = (signed char)d2;
        }
    }
    if (cin == 0) {
        scl[conv * 128 + cout] = (float)S;
        off[conv * 128 + cout] = bb[cout] - mm[cout] * invf;
        if (blk == 0) cnt[0] = 0;          // ws re-poisoned every launch
    }
}

// ---------------- IF neuron #1: x [T,B,C,H,W] f32 -> spikes NHWC i8 -----------
// fp64 membrane: bit-matches an fp64 reference's spike decisions.
__global__ void if1_kernel(const float* __restrict__ x, signed char* __restrict__ s1)
{
    const int blk = blockIdx.x;        // 1024 = B*H
    const int b   = blk >> 5;
    const int h   = blk & 31;
    const int tid = threadIdx.x;
    const int w   = tid & 31;
    const int g   = tid >> 5;          // 8 groups of 16 channels
    double v[16];
#pragma unroll
    for (int i = 0; i < 16; ++i) v[i] = 0.0;
    for (int t = 0; t < 8; ++t) {
        const size_t xbase = ((((size_t)t * 32 + b) * 128 + g * 16) * 32 + h) * 32 + w;
        unsigned wds[4] = {0u, 0u, 0u, 0u};
#pragma unroll
        for (int i = 0; i < 16; ++i) {
            v[i] += (double)x[xbase + (size_t)i * 1024];
            const bool s = (v[i] >= 1.0);
            if (s) { wds[i >> 2] |= 1u << (8 * (i & 3)); v[i] = 0.0; }
        }
        int4 pk; pk.x = wds[0]; pk.y = wds[1]; pk.z = wds[2]; pk.w = wds[3];
        *(int4*)(s1 + (((size_t)(t * 32 + b) * 1024 + h * 32 + w) * 128 + g * 16)) = pk;
    }
}

// ---------------- IF neuron #2 phase A: scan + flag near-threshold sites ------
__global__ void if2_kernel(const float* __restrict__ y1, signed char* __restrict__ s2,
                           int* __restrict__ cnt, int* __restrict__ list)
{
    const size_t idx = (size_t)blockIdx.x * 256 + threadIdx.x;  // 1,048,576 threads
    const int c4 = (int)(idx & 31);
    const int p  = (int)((idx >> 5) & 1023);
    const int b  = (int)(idx >> 15);
    float v[4];
    int flag = 0;
#pragma unroll
    for (int i = 0; i < 4; ++i) v[i] = 0.f;
    for (int t = 0; t < 8; ++t) {
        const size_t base = ((size_t)(t * 32 + b) * 1024 + p) * 128 + c4 * 4;
        const f32x4 xv = *(const f32x4*)&y1[base];
        unsigned pack = 0;
#pragma unroll
        for (int i = 0; i < 4; ++i) {
            v[i] += xv[i];
            const float d = v[i] - 1.0f;
            if (fabsf(d) < DELTA) flag |= (1 << i);
            if (d >= 0.0f) { pack |= 1u << (8 * i); v[i] = 0.f; }
        }
        *(unsigned*)(s2 + base) = pack;
    }
    if (flag) {
#pragma unroll 1
        for (int i = 0; i < 4; ++i)
            if ((flag >> i) & 1) {
                const int pos = atomicAdd(cnt, 1);
                if (pos < LIST_CAP)
                    list[pos] = (b << 17) | (p << 7) | (c4 * 4 + i);
            }
    }
}

// ---------------- IF#2 phase B: fp64 redo, one 256-thread block per site ------
__global__ __launch_bounds__(256)
void redo_kernel(const float* __restrict__ x, const float* __restrict__ w1,
                 const float* __restrict__ g1, const float* __restrict__ b1,
                 const float* __restrict__ m1, const float* __restrict__ v1r,
                 const int* __restrict__ cnt, const int* __restrict__ list,
                 signed char* __restrict__ s2)
{
    __shared__ double red[256][8];   // 16 KB
    const int count = min(cnt[0], LIST_CAP);
    const int tid = threadIdx.x;
    const int cin = tid & 127;
    const int tg  = tid >> 7;
    for (int i = blockIdx.x; i < count; i += gridDim.x) {
        const int pk = list[i];
        const int b = pk >> 17, p = (pk >> 7) & 1023, c = pk & 127;
        const int h = p >> 5, w_ = p & 31;
        double part[8];
#pragma unroll
        for (int t = 0; t < 8; ++t) part[t] = 0.0;
        const int tap0 = tg ? 5 : 0, tap1 = tg ? 9 : 5;
        for (int tap = tap0; tap < tap1; ++tap) {
            const int hh = h + tap / 3 - 1;
            const int ww = w_ + tap - (tap / 3) * 3 - 1;
            if (hh < 0 || hh > 31 || ww < 0 || ww > 31) continue;
            const int pix = hh * 32 + ww;
            const double wv = (double)w1[(size_t)(c * 128 + cin) * 9 + tap];
            double v = 0.0;
#pragma unroll
            for (int t = 0; t < 8; ++t) {
                v += (double)x[((size_t)(t * 32 + b) * 128 + cin) * 1024 + pix];
                if (v >= 1.0) { part[t] += wv; v = 0.0; }
            }
        }
#pragma unroll
        for (int t = 0; t < 8; ++t) red[tid][t] = part[t];
        __syncthreads();
        for (int s = 128; s > 0; s >>= 1) {
            if (tid < s)
#pragma unroll
                for (int t = 0; t < 8; ++t) red[tid][t] += red[tid + s][t];
            __syncthreads();
        }
        if (tid == 0) {
            const double inv  = (double)g1[c] / sqrt((double)v1r[c] + 1e-5);
            const double offc = (double)b1[c] - (double)m1[c] * inv;
            double v = 0.0;
#pragma unroll
            for (int t = 0; t < 8; ++t) {
                v += red[0][t] * inv + offc;
                const bool s = (v >= 1.0);
                s2[((size_t)(t * 32 + b) * 1024 + p) * 128 + c] = s ? 1 : 0;
                if (s) v = 0.0;
            }
        }
        __syncthreads();   // LDS reused next site
    }
}

// ---------------- conv3x3 (+folded BN) on the i8 matrix pipe ------------------
// Block: 1 image, 128-pixel strip (4 rows). NJ=2: 128 couts/block (grid 2048);
// NJ=1: 64 couts/block (grid 4096, 2 blocks/strip) so 3 digit accumulators fit
// in <=256 VGPR. Strip+halo staged in LDS once (XOR-swizzled 16B chunks).
// Per digit split s: exact i32 accumulation; epilogue combines digits in f64
// with scale S * {1, 1/254, 1/64516} then adds BN offset.
template<int NSPLIT, int NJ, bool OUT_NCHW>
__global__ __launch_bounds__(256, 2)
void conv_kernel(const signed char* __restrict__ sin, const signed char* __restrict__ wp,
                 const float* __restrict__ off, const float* __restrict__ scl,
                 float* __restrict__ out)
{
    __shared__ signed char img[6 * 34 * 128];   // 26,112 B
    const int tid = threadIdx.x;
    const int blk = blockIdx.x;
    int tb, pblk, ch;
    if (NJ == 1) { tb = blk >> 4; pblk = (blk >> 1) & 7; ch = blk & 1; }
    else         { tb = blk >> 3; pblk = blk & 7;        ch = 0;      }
    const int wn = tid >> 6;
    const int lane15 = tid & 15;
    const int q = (tid >> 4) & 3;

    // ---- stage strip + halo into LDS (halo zeroed), once ----
    const int y0 = pblk << 2;
    for (int unit = tid; unit < 1632; unit += 256) {   // 204 pixels x 8 chunks(16B)
        const int sp = unit >> 3, G = unit & 7;
        const int row = sp / 34, col = sp - row * 34;
        const int y = y0 + row - 1, xg = col - 1;
        int4 v = {0, 0, 0, 0};
        if (y >= 0 && y < 32 && xg >= 0 && xg < 32)
            v = *(const int4*)(sin + (((size_t)tb * 1024 + y * 32 + xg) * 128 + G * 16));
        *(int4*)&img[sp * 128 + ((G ^ (col & 7)) * 16)] = v;
    }
    __syncthreads();

    i32x4 acc[8][NJ][NSPLIT];
#pragma unroll
    for (int i = 0; i < 8; ++i)
#pragma unroll
        for (int j = 0; j < NJ; ++j)
#pragma unroll
            for (int s = 0; s < NSPLIT; ++s)
#pragma unroll
                for (int rg = 0; rg < 4; ++rg) acc[i][j][s][rg] = 0;

    const int cb = ch * 64 + wn * (NJ * 16);
    const signed char* wbase = wp + ((size_t)(cb + lane15) * 64 + q * 16);
#define BLOAD(s, j, kc) (*(const i32x4*)(wbase + ((size_t)((s) * 18 + (kc)) * 128 + (j) * 16) * 64))

    i32x4 buf[2][NSPLIT][NJ];
#pragma unroll
    for (int s = 0; s < NSPLIT; ++s)
#pragma unroll
        for (int j = 0; j < NJ; ++j) buf[0][s][j] = BLOAD(s, j, 0);

    for (int tap = 0; tap < 9; ++tap) {
        const int dy = tap / 3 - 1;
        const int dx = tap - (tap / 3) * 3 - 1;
#pragma unroll
        for (int ci = 0; ci < 2; ++ci) {              // 64-cin halves; kc = tap*2+ci
            const int kc  = tap * 2 + ci;
            const int kcn = kc < 17 ? kc + 1 : 17;    // kc=17: dummy re-read
#pragma unroll
            for (int s = 0; s < NSPLIT; ++s)
#pragma unroll
                for (int j = 0; j < NJ; ++j)
                    buf[(ci + 1) & 1][s][j] = BLOAD(s, j, kcn);
#pragma unroll
            for (int ih = 0; ih < 2; ++ih) {
                i32x4 af[4];
#pragma unroll
                for (int i4 = 0; i4 < 4; ++i4) {
                    const int i = ih * 4 + i4;
                    const int col = (i & 1) * 16 + lane15 + 1 + dx;
                    const int sp  = ((i >> 1) + 1 + dy) * 34 + col;
                    const int g   = (ci * 4 + q) ^ (col & 7);
                    af[i4] = *(const i32x4*)&img[sp * 128 + g * 16];
                }
#pragma unroll
                for (int s = 0; s < NSPLIT; ++s)
#pragma unroll
                    for (int j = 0; j < NJ; ++j)
#pragma unroll
                        for (int i4 = 0; i4 < 4; ++i4)
                            acc[ih * 4 + i4][j][s] = __builtin_amdgcn_mfma_i32_16x16x64_i8(
                                af[i4], buf[ci & 1][s][j], acc[ih * 4 + i4][j][s], 0, 0, 0);
            }
        }
    }
#undef BLOAD

    // epilogue: combine digits (f64, exact int inputs), +BN offset, store.
    // C/D map: col=lane&15, row=quad*4+reg (dtype-independent).
    float offv[NJ]; double sv[NJ];
#pragma unroll
    for (int j = 0; j < NJ; ++j) {
        const int c = cb + j * 16 + lane15;
        offv[j] = off[c];
        sv[j]   = (double)scl[c];
    }
#pragma unroll
    for (int i = 0; i < 8; ++i) {
        const int prow = pblk * 128 + i * 16 + q * 4;
#pragma unroll
        for (int j = 0; j < NJ; ++j) {
            const int col = cb + j * 16 + lane15;
            f32x4 vv;
#pragma unroll
            for (int rg = 0; rg < 4; ++rg) {
                double t = (double)acc[i][j][0][rg];
                if (NSPLIT >= 2) t += (double)acc[i][j][1][rg] * (1.0 / 254.0);
                if (NSPLIT >= 3) t += (double)acc[i][j][2][rg] * (1.0 / 64516.0);
                vv[rg] = (float)(t * sv[j] + (double)offv[j]);
            }
            if (OUT_NCHW) {
                *(f32x4*)&out[(size_t)tb * 131072 + (size_t)col * 1024 + prow] = vv;
            } else {
#pragma unroll
                for (int rg = 0; rg < 4; ++rg)
                    out[((size_t)tb * 1024 + prow + rg) * 128 + col] = vv[rg];
            }
        }
    }
}

extern "C" void kernel_launch(void* const* d_in, const int* in_sizes, int n_in,
                              void* d_out, int out_size, void* d_ws, size_t ws_size,
                              hipStream_t stream)
{
    const float* x  = (const float*)d_in[0];
    const float* w1 = (const float*)d_in[1];
    const float* g1 = (const float*)d_in[2];
    const float* b1 = (const float*)d_in[3];
    const float* m1 = (const float*)d_in[4];
    const float* v1 = (const float*)d_in[5];
    const float* w2 = (const float*)d_in[6];
    const float* g2 = (const float*)d_in[7];
    const float* b2 = (const float*)d_in[8];
    const float* m2 = (const float*)d_in[9];
    const float* v2 = (const float*)d_in[10];
    float* out = (float*)d_out;

    // ws layout: spikes i8 (s1 then s2 reuse) | y1 f32 | digits | off | scl | cnt | list
    char* ws = (char*)d_ws;
    signed char* s_buf = (signed char*)ws;                        //  33,554,432 B
    float*  y1   = (float*)(ws + (size_t)33554432);               // 134,217,728 B
    signed char* wp = (signed char*)(ws + (size_t)167772160);     //     737,280 B
    float*  off  = (float*)(ws + (size_t)168509440);              //       1,024 B
    float*  scl  = (float*)(ws + (size_t)168510464);              //       1,024 B
    int*    cnt  = (int*)  (ws + (size_t)168511488);              //           4 B
    int*    list = (int*)  (ws + (size_t)168512000);              //       16 MB cap

    prep_kernel<<<256, 128, 0, stream>>>(w1, g1, b1, m1, v1, w2, g2, b2, m2, v2,
                                         wp, off, scl, cnt);
    if1_kernel<<<1024, 256, 0, stream>>>(x, s_buf);
    conv_kernel<3, 1, false><<<4096, 256, 0, stream>>>(s_buf, wp, off, scl, y1);
    if2_kernel<<<4096, 256, 0, stream>>>(y1, s_buf, cnt, list);
    redo_kernel<<<2048, 256, 0, stream>>>(x, w1, g1, b1, m1, v1, cnt, list, s_buf);
    conv_kernel<2, 2, true><<<2048, 256, 0, stream>>>(s_buf, wp + 442368, off + 128,
                                                      scl + 128, out);
}